// Round 1
// baseline (714.855 us; speedup 1.0000x reference)
//
#include <hip/hip_runtime.h>
#include <math.h>

#define Bn 32
#define Ln 512
#define Dn 512
#define Hn 8
#define DHn 64
#define FFn 2048
#define Mn (Bn*Ln)   // 16384

typedef __attribute__((ext_vector_type(4))) float f32x4;
typedef __attribute__((ext_vector_type(8))) short short8;

__device__ __forceinline__ float bf2f(ushort u){ return __uint_as_float(((unsigned)u) << 16); }
__device__ __forceinline__ ushort f2bf(float f){
  unsigned u = __float_as_uint(f);
  u += 0x7FFFu + ((u >> 16) & 1u);
  return (ushort)(u >> 16);
}
__device__ __forceinline__ float gelu_tanh(float x){
  float x3 = x*x*x;
  return 0.5f*x*(1.0f + tanhf(0.7978845608028654f*(x + 0.044715f*x3)));
}

// ---------------- positional encoding table (L x D, f32) ----------------
__global__ void pe_kernel(float* __restrict__ pe){
  int idx = blockIdx.x*256 + threadIdx.x;
  if (idx >= Ln*Dn) return;
  int l = idx / Dn, d = idx - l*Dn;
  int i = d >> 1;
  float dv = expf((float)(2*i) * (-logf(10000.0f)/(float)Dn));
  float ang = (float)l * dv;
  pe[idx] = (d & 1) ? cosf(ang) : sinf(ang);
}

// ---------------- f32 -> bf16 convert ----------------
__global__ void cvt_kernel(const float* __restrict__ in, ushort* __restrict__ out, int n){
  int i = (blockIdx.x*256 + threadIdx.x)*4;
  if (i >= n) return;
  float4 v = *(const float4*)(in + i);
  ushort4 o;
  o.x = f2bf(v.x); o.y = f2bf(v.y); o.z = f2bf(v.z); o.w = f2bf(v.w);
  *(ushort4*)(out + i) = o;
}

// ---------------- GEMM: C[M x N] = A[M x K](bf16) @ W[N x K]^T(bf16), f32 acc ----------------
// Tile: BM=128, BN=64, BK=64. Block = 256 thr = 4 waves in 2x2; wave tile 64x32.
// MFMA 16x16x32 bf16; A/B frags use the same (g,j)->k bijection k = g*8+j  (consistent => correct).
// C/D layout (verified): row = (lane>>4)*4 + reg, col = lane&15.
// MODE: 0 gate (sigmoid(c)*x + spk + pe -> f32 + bf16)
//       1 bias+scale -> bf16 (q/k/v)
//       2 bias + residual -> f32 (attn_out + xin)
//       3 gelu(bias+c) -> bf16 (ff1)
//       4 gelu(bias+c) + residual -> f32 (ff2 -> out)
template<int MODE>
__global__ __launch_bounds__(256) void gemm_kernel(
    const ushort* __restrict__ A, const ushort* __restrict__ W,
    const float* __restrict__ bias,
    const float* __restrict__ res,
    const float* __restrict__ spk, const float* __restrict__ pe,
    float* __restrict__ outf, ushort* __restrict__ outb,
    int K, int N, float scale)
{
  __shared__ ushort lA[128][72];   // pad 64->72: 144B rows, 16B aligned, 2-way bank alias (free)
  __shared__ ushort lW[64][72];
  int t = threadIdx.x;
  int wave = t >> 6, lane = t & 63;
  int wr = wave >> 1, wc = wave & 1;
  int g = lane >> 4, r16 = lane & 15;
  int rowBase = blockIdx.y * 128;
  int colBase = blockIdx.x * 64;

  f32x4 acc[4][2];
  #pragma unroll
  for (int m=0;m<4;m++)
    #pragma unroll
    for (int n=0;n<2;n++) acc[m][n] = (f32x4)0.0f;

  for (int k0 = 0; k0 < K; k0 += 64){
    #pragma unroll
    for (int i=0;i<4;i++){              // A tile: 128 rows x 64 bf16
      int cid = t + i*256;
      int row = cid >> 3, c8 = (cid & 7)*8;
      float4 v = *(const float4*)(A + (size_t)(rowBase + row)*K + k0 + c8);
      *(float4*)&lA[row][c8] = v;
    }
    #pragma unroll
    for (int i=0;i<2;i++){              // W tile: 64 rows x 64 bf16
      int cid = t + i*256;
      int row = cid >> 3, c8 = (cid & 7)*8;
      float4 v = *(const float4*)(W + (size_t)(colBase + row)*K + k0 + c8);
      *(float4*)&lW[row][c8] = v;
    }
    __syncthreads();
    #pragma unroll
    for (int ks=0; ks<2; ks++){
      short8 af[4], bfr[2];
      #pragma unroll
      for (int m=0;m<4;m++)
        af[m] = *(const short8*)&lA[wr*64 + m*16 + r16][ks*32 + g*8];
      #pragma unroll
      for (int n=0;n<2;n++)
        bfr[n] = *(const short8*)&lW[wc*32 + n*16 + r16][ks*32 + g*8];
      #pragma unroll
      for (int m=0;m<4;m++)
        #pragma unroll
        for (int n=0;n<2;n++)
          acc[m][n] = __builtin_amdgcn_mfma_f32_16x16x32_bf16(af[m], bfr[n], acc[m][n], 0, 0, 0);
    }
    __syncthreads();
  }

  #pragma unroll
  for (int m=0;m<4;m++){
    #pragma unroll
    for (int n=0;n<2;n++){
      #pragma unroll
      for (int j=0;j<4;j++){
        int gr = rowBase + wr*64 + m*16 + g*4 + j;
        int gc = colBase + wc*32 + n*16 + r16;
        size_t o = (size_t)gr * N + gc;
        float c = acc[m][n][j];
        if constexpr (MODE == 0){
          float s = 1.0f/(1.0f + expf(-c));
          float rv = s * res[o] + spk[o] + pe[(gr & (Ln-1))*Dn + gc];
          outf[o] = rv; outb[o] = f2bf(rv);
        } else if constexpr (MODE == 1){
          outb[o] = f2bf((c + bias[gc]) * scale);
        } else if constexpr (MODE == 2){
          outf[o] = c + bias[gc] + res[o];
        } else if constexpr (MODE == 3){
          outb[o] = f2bf(gelu_tanh(c + bias[gc]));
        } else {
          outf[o] = gelu_tanh(c + bias[gc]) + res[o];
        }
      }
    }
  }
}

// ---------------- attention: per-thread q-row, online softmax, LDS-staged K/V ----------------
// grid (L/256, H, B), 256 threads; K/V staged in 64-row blocks as f32 (uniform broadcast reads).
__global__ __launch_bounds__(256) void attn_kernel(
    const ushort* __restrict__ qb, const ushort* __restrict__ kb, const ushort* __restrict__ vb,
    const int* __restrict__ mask, ushort* __restrict__ ctxb)
{
  __shared__ float lK[64][64];
  __shared__ float lV[64][64];
  int t = threadIdx.x;
  int b = blockIdx.z, h = blockIdx.y;
  int qrow = blockIdx.x*256 + t;

  const ushort* qp = qb + (size_t)(b*Ln + qrow)*Dn + h*DHn;
  float q[64];
  #pragma unroll
  for (int c8=0; c8<8; c8++){
    short8 v = *(const short8*)(qp + c8*8);
    #pragma unroll
    for (int j=0;j<8;j++) q[c8*8+j] = bf2f((ushort)v[j]);
  }
  float ctx[64];
  #pragma unroll
  for (int d=0; d<64; d++) ctx[d] = 0.0f;
  float mrun = -INFINITY, lrun = 0.0f;

  for (int kb0 = 0; kb0 < Ln; kb0 += 64){
    #pragma unroll
    for (int i=0;i<2;i++){
      int cid = t + i*256;
      int row = cid >> 3, c8 = (cid & 7)*8;
      short8 kv = *(const short8*)(kb + (size_t)(b*Ln + kb0 + row)*Dn + h*DHn + c8);
      short8 vv = *(const short8*)(vb + (size_t)(b*Ln + kb0 + row)*Dn + h*DHn + c8);
      #pragma unroll
      for (int j=0;j<8;j++){
        lK[row][c8+j] = bf2f((ushort)kv[j]);
        lV[row][c8+j] = bf2f((ushort)vv[j]);
      }
    }
    __syncthreads();
    for (int kk=0; kk<64; kk++){
      float s0=0.f,s1=0.f,s2=0.f,s3=0.f;
      #pragma unroll
      for (int d=0; d<64; d+=4){
        s0 += q[d+0]*lK[kk][d+0];
        s1 += q[d+1]*lK[kk][d+1];
        s2 += q[d+2]*lK[kk][d+2];
        s3 += q[d+3]*lK[kk][d+3];
      }
      float s = (s0+s1)+(s2+s3);
      if (mask[b*Ln + kb0 + kk] == 0) s = -1e10f;
      if (s > mrun){
        float al = __expf(mrun - s);
        lrun *= al;
        #pragma unroll
        for (int d=0; d<64; d++) ctx[d] *= al;
        mrun = s;
      }
      float p = __expf(s - mrun);
      lrun += p;
      #pragma unroll
      for (int d=0; d<64; d++) ctx[d] += p * lV[kk][d];
    }
    __syncthreads();
  }
  float inv = 1.0f / lrun;
  ushort* cp = ctxb + (size_t)(b*Ln + qrow)*Dn + h*DHn;
  #pragma unroll
  for (int d4=0; d4<16; d4++){
    ushort4 o;
    o.x = f2bf(ctx[d4*4+0]*inv);
    o.y = f2bf(ctx[d4*4+1]*inv);
    o.z = f2bf(ctx[d4*4+2]*inv);
    o.w = f2bf(ctx[d4*4+3]*inv);
    *(ushort4*)(cp + d4*4) = o;
  }
}

// ---------------- layernorm: one wave per row (D=512), out bf16 ----------------
__global__ __launch_bounds__(256) void ln_kernel(
    const float* __restrict__ hbuf, const float* __restrict__ gamma, const float* __restrict__ beta,
    ushort* __restrict__ out)
{
  int row = blockIdx.x*4 + (threadIdx.x >> 6);
  int lane = threadIdx.x & 63;
  const float* p = hbuf + (size_t)row*Dn + lane*8;
  float4 a = *(const float4*)p;
  float4 c = *(const float4*)(p + 4);
  float v[8] = {a.x,a.y,a.z,a.w,c.x,c.y,c.z,c.w};
  float s = 0.f, ss = 0.f;
  #pragma unroll
  for (int j=0;j<8;j++){ s += v[j]; ss += v[j]*v[j]; }
  #pragma unroll
  for (int off=32; off>0; off>>=1){ s += __shfl_xor(s, off); ss += __shfl_xor(ss, off); }
  float mu = s * (1.0f/Dn);
  float var = ss * (1.0f/Dn) - mu*mu;
  float rstd = rsqrtf(var + 1e-5f);
  ushort o8[8];
  #pragma unroll
  for (int j=0;j<8;j++) o8[j] = f2bf((v[j]-mu)*rstd*gamma[lane*8+j] + beta[lane*8+j]);
  ushort* op = out + (size_t)row*Dn + lane*8;
  *(ushort4*)op       = make_ushort4(o8[0],o8[1],o8[2],o8[3]);
  *(ushort4*)(op + 4) = make_ushort4(o8[4],o8[5],o8[6],o8[7]);
}

extern "C" void kernel_launch(void* const* d_in, const int* in_sizes, int n_in,
                              void* d_out, int out_size, void* d_ws, size_t ws_size,
                              hipStream_t stream) {
  (void)in_sizes; (void)n_in; (void)out_size; (void)ws_size;
  const float* x    = (const float*)d_in[0];
  const int*   mask = (const int*)d_in[1];
  const float* spk  = (const float*)d_in[2];
  const float* Wg   = (const float*)d_in[3];
  const float* Wq   = (const float*)d_in[4];  const float* bq = (const float*)d_in[5];
  const float* Wk   = (const float*)d_in[6];  const float* bk = (const float*)d_in[7];
  const float* Wv   = (const float*)d_in[8];  const float* bv = (const float*)d_in[9];
  const float* Wo   = (const float*)d_in[10]; const float* bo = (const float*)d_in[11];
  const float* lng  = (const float*)d_in[12]; const float* lnbeta = (const float*)d_in[13];
  const float* W1   = (const float*)d_in[14]; const float* b1 = (const float*)d_in[15];
  const float* W2   = (const float*)d_in[16]; const float* b2 = (const float*)d_in[17];
  float* out = (float*)d_out;

  char* w = (char*)d_ws;
  size_t o = 0;
  ushort* xbf   = (ushort*)(w + o); o += (size_t)Mn*Dn*2;   // dead after gate  } overlapped
  ushort* xinb  = (ushort*)(w + o); o += (size_t)Mn*Dn*2;   // dead after v     } by midb
  ushort* qbuf  = (ushort*)(w + o); o += (size_t)Mn*Dn*2;   // dead after attn  } (67.1MB)
  ushort* kbuf  = (ushort*)(w + o); o += (size_t)Mn*Dn*2;   // dead after attn  }
  ushort* vbuf  = (ushort*)(w + o); o += (size_t)Mn*Dn*2;
  ushort* ctxb  = (ushort*)(w + o); o += (size_t)Mn*Dn*2;
  float*  xinf  = (float*)(w + o);  o += (size_t)Mn*Dn*4;
  float*  hbuf  = (float*)(w + o);  o += (size_t)Mn*Dn*4;
  ushort* lnbuf = (ushort*)(w + o); o += (size_t)Mn*Dn*2;
  ushort* wgb   = (ushort*)(w + o); o += (size_t)Dn*Dn*2;
  ushort* wqb   = (ushort*)(w + o); o += (size_t)Dn*Dn*2;
  ushort* wkb   = (ushort*)(w + o); o += (size_t)Dn*Dn*2;
  ushort* wvb   = (ushort*)(w + o); o += (size_t)Dn*Dn*2;
  ushort* wob   = (ushort*)(w + o); o += (size_t)Dn*Dn*2;
  ushort* w1b   = (ushort*)(w + o); o += (size_t)FFn*Dn*2;
  ushort* w2b   = (ushort*)(w + o); o += (size_t)Dn*FFn*2;
  float*  pebuf = (float*)(w + o);  o += (size_t)Ln*Dn*4;
  ushort* midb  = xbf;  // M x FF bf16, overlaps xbf..kbuf (all dead by then)

  hipLaunchKernelGGL(pe_kernel, dim3((Ln*Dn)/256), dim3(256), 0, stream, pebuf);
  hipLaunchKernelGGL(cvt_kernel, dim3((Mn*Dn/4)/256), dim3(256), 0, stream, x, xbf, Mn*Dn);
  hipLaunchKernelGGL(cvt_kernel, dim3((Dn*Dn/4)/256), dim3(256), 0, stream, Wg, wgb, Dn*Dn);
  hipLaunchKernelGGL(cvt_kernel, dim3((Dn*Dn/4)/256), dim3(256), 0, stream, Wq, wqb, Dn*Dn);
  hipLaunchKernelGGL(cvt_kernel, dim3((Dn*Dn/4)/256), dim3(256), 0, stream, Wk, wkb, Dn*Dn);
  hipLaunchKernelGGL(cvt_kernel, dim3((Dn*Dn/4)/256), dim3(256), 0, stream, Wv, wvb, Dn*Dn);
  hipLaunchKernelGGL(cvt_kernel, dim3((Dn*Dn/4)/256), dim3(256), 0, stream, Wo, wob, Dn*Dn);
  hipLaunchKernelGGL(cvt_kernel, dim3((FFn*Dn/4)/256), dim3(256), 0, stream, W1, w1b, FFn*Dn);
  hipLaunchKernelGGL(cvt_kernel, dim3((FFn*Dn/4)/256), dim3(256), 0, stream, W2, w2b, FFn*Dn);

  // gate: xin = sigmoid(x@Wg^T)*x + spk + pe  -> xinf (f32) + xinb (bf16)
  hipLaunchKernelGGL((gemm_kernel<0>), dim3(Dn/64, Mn/128), dim3(256), 0, stream,
                     xbf, wgb, (const float*)nullptr, x, spk, pebuf, xinf, xinb, Dn, Dn, 1.0f);
  // q/k/v
  hipLaunchKernelGGL((gemm_kernel<1>), dim3(Dn/64, Mn/128), dim3(256), 0, stream,
                     xinb, wqb, bq, (const float*)nullptr, (const float*)nullptr, (const float*)nullptr,
                     (float*)nullptr, qbuf, Dn, Dn, 0.125f);
  hipLaunchKernelGGL((gemm_kernel<1>), dim3(Dn/64, Mn/128), dim3(256), 0, stream,
                     xinb, wkb, bk, (const float*)nullptr, (const float*)nullptr, (const float*)nullptr,
                     (float*)nullptr, kbuf, Dn, Dn, 1.0f);
  hipLaunchKernelGGL((gemm_kernel<1>), dim3(Dn/64, Mn/128), dim3(256), 0, stream,
                     xinb, wvb, bv, (const float*)nullptr, (const float*)nullptr, (const float*)nullptr,
                     (float*)nullptr, vbuf, Dn, Dn, 1.0f);
  // attention
  hipLaunchKernelGGL(attn_kernel, dim3(Ln/256, Hn, Bn), dim3(256), 0, stream,
                     qbuf, kbuf, vbuf, mask, ctxb);
  // h = ctx@Wo^T + bo + xin
  hipLaunchKernelGGL((gemm_kernel<2>), dim3(Dn/64, Mn/128), dim3(256), 0, stream,
                     ctxb, wob, bo, xinf, (const float*)nullptr, (const float*)nullptr,
                     hbuf, (ushort*)nullptr, Dn, Dn, 1.0f);
  // layernorm
  hipLaunchKernelGGL(ln_kernel, dim3(Mn/4), dim3(256), 0, stream, hbuf, lng, lnbeta, lnbuf);
  // mid = gelu(ln@W1^T + b1)
  hipLaunchKernelGGL((gemm_kernel<3>), dim3(FFn/64, Mn/128), dim3(256), 0, stream,
                     lnbuf, w1b, b1, (const float*)nullptr, (const float*)nullptr, (const float*)nullptr,
                     (float*)nullptr, midb, Dn, FFn, 1.0f);
  // out = gelu(mid@W2^T + b2) + h
  hipLaunchKernelGGL((gemm_kernel<4>), dim3(Dn/64, Mn/128), dim3(256), 0, stream,
                     midb, w2b, b2, hbuf, (const float*)nullptr, (const float*)nullptr,
                     out, (ushort*)nullptr, FFn, Dn, 1.0f);
}

// Round 2
// 441.405 us; speedup vs baseline: 1.6195x; 1.6195x over previous
//
#include <hip/hip_runtime.h>
#include <math.h>

#define Bn 32
#define Ln 512
#define Dn 512
#define Hn 8
#define DHn 64
#define FFn 2048
#define Mn (Bn*Ln)   // 16384

typedef __attribute__((ext_vector_type(4))) float f32x4;
typedef __attribute__((ext_vector_type(8))) short short8;

__device__ __forceinline__ float bf2f(ushort u){ return __uint_as_float(((unsigned)u) << 16); }
__device__ __forceinline__ ushort f2bf(float f){
  unsigned u = __float_as_uint(f);
  u += 0x7FFFu + ((u >> 16) & 1u);
  return (ushort)(u >> 16);
}
__device__ __forceinline__ float gelu_tanh(float x){
  float x3 = x*x*x;
  return 0.5f*x*(1.0f + tanhf(0.7978845608028654f*(x + 0.044715f*x3)));
}

// ---------------- positional encoding table (L x D, f32) ----------------
__global__ void pe_kernel(float* __restrict__ pe){
  int idx = blockIdx.x*256 + threadIdx.x;
  if (idx >= Ln*Dn) return;
  int l = idx / Dn, d = idx - l*Dn;
  int i = d >> 1;
  float dv = expf((float)(2*i) * (-logf(10000.0f)/(float)Dn));
  float ang = (float)l * dv;
  pe[idx] = (d & 1) ? cosf(ang) : sinf(ang);
}

// ---------------- f32 -> bf16 convert ----------------
__global__ void cvt_kernel(const float* __restrict__ in, ushort* __restrict__ out, int n){
  int i = (blockIdx.x*256 + threadIdx.x)*4;
  if (i >= n) return;
  float4 v = *(const float4*)(in + i);
  ushort4 o;
  o.x = f2bf(v.x); o.y = f2bf(v.y); o.z = f2bf(v.z); o.w = f2bf(v.w);
  *(ushort4*)(out + i) = o;
}

// ---------------- GEMM: C[M x N] = A[M x K](bf16) @ W[N x K]^T(bf16), f32 acc ----------------
// Tile: BM=128, BN=64, BK=64. Block = 256 thr = 4 waves in 2x2; wave tile 64x32.
// MFMA 16x16x32 bf16; A/B frags use the same (g,j)->k bijection (consistent => correct).
// C/D layout (verified): row = (lane>>4)*4 + reg, col = lane&15.
template<int MODE>
__global__ __launch_bounds__(256) void gemm_kernel(
    const ushort* __restrict__ A, const ushort* __restrict__ W,
    const float* __restrict__ bias,
    const float* __restrict__ res,
    const float* __restrict__ spk, const float* __restrict__ pe,
    float* __restrict__ outf, ushort* __restrict__ outb,
    int K, int N, float scale)
{
  __shared__ ushort lA[128][72];   // pad 64->72: 144B rows, 16B aligned, 2-way bank alias (free)
  __shared__ ushort lW[64][72];
  int t = threadIdx.x;
  int wave = t >> 6, lane = t & 63;
  int wr = wave >> 1, wc = wave & 1;
  int g = lane >> 4, r16 = lane & 15;
  int rowBase = blockIdx.y * 128;
  int colBase = blockIdx.x * 64;

  f32x4 acc[4][2];
  #pragma unroll
  for (int m=0;m<4;m++)
    #pragma unroll
    for (int n=0;n<2;n++) acc[m][n] = (f32x4)0.0f;

  for (int k0 = 0; k0 < K; k0 += 64){
    #pragma unroll
    for (int i=0;i<4;i++){              // A tile: 128 rows x 64 bf16
      int cid = t + i*256;
      int row = cid >> 3, c8 = (cid & 7)*8;
      float4 v = *(const float4*)(A + (size_t)(rowBase + row)*K + k0 + c8);
      *(float4*)&lA[row][c8] = v;
    }
    #pragma unroll
    for (int i=0;i<2;i++){              // W tile: 64 rows x 64 bf16
      int cid = t + i*256;
      int row = cid >> 3, c8 = (cid & 7)*8;
      float4 v = *(const float4*)(W + (size_t)(colBase + row)*K + k0 + c8);
      *(float4*)&lW[row][c8] = v;
    }
    __syncthreads();
    #pragma unroll
    for (int ks=0; ks<2; ks++){
      short8 af[4], bfr[2];
      #pragma unroll
      for (int m=0;m<4;m++)
        af[m] = *(const short8*)&lA[wr*64 + m*16 + r16][ks*32 + g*8];
      #pragma unroll
      for (int n=0;n<2;n++)
        bfr[n] = *(const short8*)&lW[wc*32 + n*16 + r16][ks*32 + g*8];
      #pragma unroll
      for (int m=0;m<4;m++)
        #pragma unroll
        for (int n=0;n<2;n++)
          acc[m][n] = __builtin_amdgcn_mfma_f32_16x16x32_bf16(af[m], bfr[n], acc[m][n], 0, 0, 0);
    }
    __syncthreads();
  }

  #pragma unroll
  for (int m=0;m<4;m++){
    #pragma unroll
    for (int n=0;n<2;n++){
      #pragma unroll
      for (int j=0;j<4;j++){
        int gr = rowBase + wr*64 + m*16 + g*4 + j;
        int gc = colBase + wc*32 + n*16 + r16;
        size_t o = (size_t)gr * N + gc;
        float c = acc[m][n][j];
        if constexpr (MODE == 0){
          float s = 1.0f/(1.0f + expf(-c));
          float rv = s * res[o] + spk[o] + pe[(gr & (Ln-1))*Dn + gc];
          outf[o] = rv; outb[o] = f2bf(rv);
        } else if constexpr (MODE == 1){
          outb[o] = f2bf((c + bias[gc]) * scale);
        } else if constexpr (MODE == 2){
          outf[o] = c + bias[gc] + res[o];
        } else if constexpr (MODE == 3){
          outb[o] = f2bf(gelu_tanh(c + bias[gc]));
        } else {
          outf[o] = gelu_tanh(c + bias[gc]) + res[o];
        }
      }
    }
  }
}

// ---------------- MFMA flash attention ----------------
// grid (L/128, H, B), 256 thr = 4 waves; wave w owns 32 q-rows.
// K tile [64][72] and V^T tile [64][72] staged in LDS (shared); P re-fragmented
// through wave-private LDS [32][72] (no barrier needed for P).
// Q pre-scaled by 1/sqrt(DH) upstream. Online softmax per q-row:
// row r = m*16+g*4+j lives in the 16 lanes sharing g (reduce via shfl_xor 1,2,4,8).
__global__ __launch_bounds__(256) void attn_mfma_kernel(
    const ushort* __restrict__ qb, const ushort* __restrict__ kb, const ushort* __restrict__ vb,
    const int* __restrict__ mask, ushort* __restrict__ ctxb)
{
  __shared__ ushort lK[64][72];
  __shared__ ushort lVt[64][72];   // V transposed: [dh][key]
  __shared__ ushort lP[4][32][72]; // wave-private P staging

  int t = threadIdx.x;
  int w = t >> 6, lane = t & 63;
  int g = lane >> 4, r16 = lane & 15;
  int b = blockIdx.z, h = blockIdx.y;
  int qbase = blockIdx.x*128 + w*32;

  // Q fragments: rows qbase + m*16 + r16, k-slice ks*32 + g*8
  short8 af_q[2][2];
  #pragma unroll
  for (int m=0;m<2;m++)
    #pragma unroll
    for (int ks=0;ks<2;ks++)
      af_q[m][ks] = *(const short8*)(qb + (size_t)(b*Ln + qbase + m*16 + r16)*Dn + h*DHn + ks*32 + g*8);

  f32x4 acc_ctx[2][4];
  #pragma unroll
  for (int m=0;m<2;m++)
    #pragma unroll
    for (int n=0;n<4;n++) acc_ctx[m][n] = (f32x4)0.0f;
  float mrun[2][4], lrun[2][4];
  #pragma unroll
  for (int m=0;m<2;m++)
    #pragma unroll
    for (int j=0;j<4;j++){ mrun[m][j] = -INFINITY; lrun[m][j] = 0.0f; }

  for (int kb0 = 0; kb0 < Ln; kb0 += 64){
    __syncthreads();   // previous tile's K/V reads complete
    #pragma unroll
    for (int i=0;i<2;i++){
      int cid = t + i*256;
      int key = cid >> 3, c8 = (cid & 7)*8;
      short8 kv = *(const short8*)(kb + (size_t)(b*Ln + kb0 + key)*Dn + h*DHn + c8);
      short8 vv = *(const short8*)(vb + (size_t)(b*Ln + kb0 + key)*Dn + h*DHn + c8);
      *(short8*)&lK[key][c8] = kv;
      #pragma unroll
      for (int j=0;j<8;j++) lVt[c8+j][key] = (ushort)vv[j];
    }
    __syncthreads();

    // S = Q @ K^T   (rows = q, cols = key)
    f32x4 acc_s[2][4];
    #pragma unroll
    for (int m=0;m<2;m++)
      #pragma unroll
      for (int n=0;n<4;n++) acc_s[m][n] = (f32x4)0.0f;
    #pragma unroll
    for (int ks=0;ks<2;ks++){
      short8 bf_k[4];
      #pragma unroll
      for (int n=0;n<4;n++)
        bf_k[n] = *(const short8*)&lK[n*16 + r16][ks*32 + g*8];
      #pragma unroll
      for (int m=0;m<2;m++)
        #pragma unroll
        for (int n=0;n<4;n++)
          acc_s[m][n] = __builtin_amdgcn_mfma_f32_16x16x32_bf16(af_q[m][ks], bf_k[n], acc_s[m][n], 0, 0, 0);
    }

    // mask keys (key = kb0 + n*16 + r16; same for both m, all j)
    #pragma unroll
    for (int n=0;n<4;n++){
      if (mask[b*Ln + kb0 + n*16 + r16] == 0){
        #pragma unroll
        for (int m=0;m<2;m++)
          #pragma unroll
          for (int j=0;j<4;j++) acc_s[m][n][j] = -1e10f;
      }
    }

    // online softmax; P -> bf16 in wave-private LDS
    #pragma unroll
    for (int m=0;m<2;m++){
      #pragma unroll
      for (int j=0;j<4;j++){
        float tmax = fmaxf(fmaxf(acc_s[m][0][j], acc_s[m][1][j]),
                           fmaxf(acc_s[m][2][j], acc_s[m][3][j]));
        #pragma unroll
        for (int off=1; off<16; off<<=1) tmax = fmaxf(tmax, __shfl_xor(tmax, off));
        float newm = fmaxf(mrun[m][j], tmax);
        float alpha = __expf(mrun[m][j] - newm);
        float p0 = __expf(acc_s[m][0][j] - newm);
        float p1 = __expf(acc_s[m][1][j] - newm);
        float p2 = __expf(acc_s[m][2][j] - newm);
        float p3 = __expf(acc_s[m][3][j] - newm);
        float tsum = (p0+p1)+(p2+p3);
        #pragma unroll
        for (int off=1; off<16; off<<=1) tsum += __shfl_xor(tsum, off);
        lrun[m][j] = lrun[m][j]*alpha + tsum;
        mrun[m][j] = newm;
        #pragma unroll
        for (int n2=0;n2<4;n2++) acc_ctx[m][n2][j] *= alpha;
        int prow = m*16 + g*4 + j;
        lP[w][prow][0*16 + r16] = f2bf(p0);
        lP[w][prow][1*16 + r16] = f2bf(p1);
        lP[w][prow][2*16 + r16] = f2bf(p2);
        lP[w][prow][3*16 + r16] = f2bf(p3);
      }
    }

    // ctx += P @ V   (A = P[32][64] keys-major, B = V^T[dh][key])
    #pragma unroll
    for (int ks2=0;ks2<2;ks2++){
      short8 af_p[2], bf_v[4];
      #pragma unroll
      for (int m=0;m<2;m++)
        af_p[m] = *(const short8*)&lP[w][m*16 + r16][ks2*32 + g*8];
      #pragma unroll
      for (int n=0;n<4;n++)
        bf_v[n] = *(const short8*)&lVt[n*16 + r16][ks2*32 + g*8];
      #pragma unroll
      for (int m=0;m<2;m++)
        #pragma unroll
        for (int n=0;n<4;n++)
          acc_ctx[m][n] = __builtin_amdgcn_mfma_f32_16x16x32_bf16(af_p[m], bf_v[n], acc_ctx[m][n], 0, 0, 0);
    }
  }

  // write ctx (bf16): row qbase+m*16+g*4+j, col n*16+r16
  #pragma unroll
  for (int m=0;m<2;m++){
    #pragma unroll
    for (int j=0;j<4;j++){
      float inv = 1.0f / lrun[m][j];
      int gr = qbase + m*16 + g*4 + j;
      #pragma unroll
      for (int n=0;n<4;n++){
        ctxb[(size_t)(b*Ln + gr)*Dn + h*DHn + n*16 + r16] = f2bf(acc_ctx[m][n][j] * inv);
      }
    }
  }
}

// ---------------- layernorm: one wave per row (D=512), out bf16 ----------------
__global__ __launch_bounds__(256) void ln_kernel(
    const float* __restrict__ hbuf, const float* __restrict__ gamma, const float* __restrict__ beta,
    ushort* __restrict__ out)
{
  int row = blockIdx.x*4 + (threadIdx.x >> 6);
  int lane = threadIdx.x & 63;
  const float* p = hbuf + (size_t)row*Dn + lane*8;
  float4 a = *(const float4*)p;
  float4 c = *(const float4*)(p + 4);
  float v[8] = {a.x,a.y,a.z,a.w,c.x,c.y,c.z,c.w};
  float s = 0.f, ss = 0.f;
  #pragma unroll
  for (int j=0;j<8;j++){ s += v[j]; ss += v[j]*v[j]; }
  #pragma unroll
  for (int off=32; off>0; off>>=1){ s += __shfl_xor(s, off); ss += __shfl_xor(ss, off); }
  float mu = s * (1.0f/Dn);
  float var = ss * (1.0f/Dn) - mu*mu;
  float rstd = rsqrtf(var + 1e-5f);
  ushort o8[8];
  #pragma unroll
  for (int j=0;j<8;j++) o8[j] = f2bf((v[j]-mu)*rstd*gamma[lane*8+j] + beta[lane*8+j]);
  ushort* op = out + (size_t)row*Dn + lane*8;
  *(ushort4*)op       = make_ushort4(o8[0],o8[1],o8[2],o8[3]);
  *(ushort4*)(op + 4) = make_ushort4(o8[4],o8[5],o8[6],o8[7]);
}

extern "C" void kernel_launch(void* const* d_in, const int* in_sizes, int n_in,
                              void* d_out, int out_size, void* d_ws, size_t ws_size,
                              hipStream_t stream) {
  (void)in_sizes; (void)n_in; (void)out_size; (void)ws_size;
  const float* x    = (const float*)d_in[0];
  const int*   mask = (const int*)d_in[1];
  const float* spk  = (const float*)d_in[2];
  const float* Wg   = (const float*)d_in[3];
  const float* Wq   = (const float*)d_in[4];  const float* bq = (const float*)d_in[5];
  const float* Wk   = (const float*)d_in[6];  const float* bk = (const float*)d_in[7];
  const float* Wv   = (const float*)d_in[8];  const float* bv = (const float*)d_in[9];
  const float* Wo   = (const float*)d_in[10]; const float* bo = (const float*)d_in[11];
  const float* lng  = (const float*)d_in[12]; const float* lnbeta = (const float*)d_in[13];
  const float* W1   = (const float*)d_in[14]; const float* b1 = (const float*)d_in[15];
  const float* W2   = (const float*)d_in[16]; const float* b2 = (const float*)d_in[17];
  float* out = (float*)d_out;

  char* w = (char*)d_ws;
  size_t o = 0;
  ushort* xbf   = (ushort*)(w + o); o += (size_t)Mn*Dn*2;   // dead after gate  } overlapped
  ushort* xinb  = (ushort*)(w + o); o += (size_t)Mn*Dn*2;   // dead after v     } by midb
  ushort* qbuf  = (ushort*)(w + o); o += (size_t)Mn*Dn*2;   // dead after attn  } (67.1MB)
  ushort* kbuf  = (ushort*)(w + o); o += (size_t)Mn*Dn*2;   // dead after attn  }
  ushort* vbuf  = (ushort*)(w + o); o += (size_t)Mn*Dn*2;
  ushort* ctxb  = (ushort*)(w + o); o += (size_t)Mn*Dn*2;
  float*  xinf  = (float*)(w + o);  o += (size_t)Mn*Dn*4;
  float*  hbuf  = (float*)(w + o);  o += (size_t)Mn*Dn*4;
  ushort* lnbuf = (ushort*)(w + o); o += (size_t)Mn*Dn*2;
  ushort* wgb   = (ushort*)(w + o); o += (size_t)Dn*Dn*2;
  ushort* wqb   = (ushort*)(w + o); o += (size_t)Dn*Dn*2;
  ushort* wkb   = (ushort*)(w + o); o += (size_t)Dn*Dn*2;
  ushort* wvb   = (ushort*)(w + o); o += (size_t)Dn*Dn*2;
  ushort* wob   = (ushort*)(w + o); o += (size_t)Dn*Dn*2;
  ushort* w1b   = (ushort*)(w + o); o += (size_t)FFn*Dn*2;
  ushort* w2b   = (ushort*)(w + o); o += (size_t)Dn*FFn*2;
  float*  pebuf = (float*)(w + o);  o += (size_t)Ln*Dn*4;
  ushort* midb  = xbf;  // M x FF bf16, overlaps xbf..kbuf (all dead by then)

  hipLaunchKernelGGL(pe_kernel, dim3((Ln*Dn)/256), dim3(256), 0, stream, pebuf);
  hipLaunchKernelGGL(cvt_kernel, dim3((Mn*Dn/4)/256), dim3(256), 0, stream, x, xbf, Mn*Dn);
  hipLaunchKernelGGL(cvt_kernel, dim3((Dn*Dn/4)/256), dim3(256), 0, stream, Wg, wgb, Dn*Dn);
  hipLaunchKernelGGL(cvt_kernel, dim3((Dn*Dn/4)/256), dim3(256), 0, stream, Wq, wqb, Dn*Dn);
  hipLaunchKernelGGL(cvt_kernel, dim3((Dn*Dn/4)/256), dim3(256), 0, stream, Wk, wkb, Dn*Dn);
  hipLaunchKernelGGL(cvt_kernel, dim3((Dn*Dn/4)/256), dim3(256), 0, stream, Wv, wvb, Dn*Dn);
  hipLaunchKernelGGL(cvt_kernel, dim3((Dn*Dn/4)/256), dim3(256), 0, stream, Wo, wob, Dn*Dn);
  hipLaunchKernelGGL(cvt_kernel, dim3((FFn*Dn/4)/256), dim3(256), 0, stream, W1, w1b, FFn*Dn);
  hipLaunchKernelGGL(cvt_kernel, dim3((FFn*Dn/4)/256), dim3(256), 0, stream, W2, w2b, FFn*Dn);

  // gate: xin = sigmoid(x@Wg^T)*x + spk + pe  -> xinf (f32) + xinb (bf16)
  hipLaunchKernelGGL((gemm_kernel<0>), dim3(Dn/64, Mn/128), dim3(256), 0, stream,
                     xbf, wgb, (const float*)nullptr, x, spk, pebuf, xinf, xinb, Dn, Dn, 1.0f);
  // q/k/v
  hipLaunchKernelGGL((gemm_kernel<1>), dim3(Dn/64, Mn/128), dim3(256), 0, stream,
                     xinb, wqb, bq, (const float*)nullptr, (const float*)nullptr, (const float*)nullptr,
                     (float*)nullptr, qbuf, Dn, Dn, 0.125f);
  hipLaunchKernelGGL((gemm_kernel<1>), dim3(Dn/64, Mn/128), dim3(256), 0, stream,
                     xinb, wkb, bk, (const float*)nullptr, (const float*)nullptr, (const float*)nullptr,
                     (float*)nullptr, kbuf, Dn, Dn, 1.0f);
  hipLaunchKernelGGL((gemm_kernel<1>), dim3(Dn/64, Mn/128), dim3(256), 0, stream,
                     xinb, wvb, bv, (const float*)nullptr, (const float*)nullptr, (const float*)nullptr,
                     (float*)nullptr, vbuf, Dn, Dn, 1.0f);
  // attention (MFMA flash)
  hipLaunchKernelGGL(attn_mfma_kernel, dim3(Ln/128, Hn, Bn), dim3(256), 0, stream,
                     qbuf, kbuf, vbuf, mask, ctxb);
  // h = ctx@Wo^T + bo + xin
  hipLaunchKernelGGL((gemm_kernel<2>), dim3(Dn/64, Mn/128), dim3(256), 0, stream,
                     ctxb, wob, bo, xinf, (const float*)nullptr, (const float*)nullptr,
                     hbuf, (ushort*)nullptr, Dn, Dn, 1.0f);
  // layernorm
  hipLaunchKernelGGL(ln_kernel, dim3(Mn/4), dim3(256), 0, stream, hbuf, lng, lnbeta, lnbuf);
  // mid = gelu(ln@W1^T + b1)
  hipLaunchKernelGGL((gemm_kernel<3>), dim3(FFn/64, Mn/128), dim3(256), 0, stream,
                     lnbuf, w1b, b1, (const float*)nullptr, (const float*)nullptr, (const float*)nullptr,
                     (float*)nullptr, midb, Dn, FFn, 1.0f);
  // out = gelu(mid@W2^T + b2) + h
  hipLaunchKernelGGL((gemm_kernel<4>), dim3(Dn/64, Mn/128), dim3(256), 0, stream,
                     midb, w2b, b2, hbuf, (const float*)nullptr, (const float*)nullptr,
                     out, (ushort*)nullptr, FFn, Dn, 1.0f);
}

// Round 3
// 383.200 us; speedup vs baseline: 1.8655x; 1.1519x over previous
//
#include <hip/hip_runtime.h>
#include <math.h>

#define Bn 32
#define Ln 512
#define Dn 512
#define Hn 8
#define DHn 64
#define FFn 2048
#define Mn (Bn*Ln)   // 16384

typedef __attribute__((ext_vector_type(4))) float f32x4;
typedef __attribute__((ext_vector_type(8))) short short8;

__device__ __forceinline__ float bf2f(ushort u){ return __uint_as_float(((unsigned)u) << 16); }
__device__ __forceinline__ ushort f2bf(float f){
  unsigned u = __float_as_uint(f);
  u += 0x7FFFu + ((u >> 16) & 1u);
  return (ushort)(u >> 16);
}
__device__ __forceinline__ float gelu_tanh(float x){
  float x3 = x*x*x;
  return 0.5f*x*(1.0f + tanhf(0.7978845608028654f*(x + 0.044715f*x3)));
}

// async global->LDS, 16B per lane; LDS dest is wave-uniform base + lane*16
__device__ __forceinline__ void gload_lds16(const ushort* g, ushort* l){
  __builtin_amdgcn_global_load_lds(
      (__attribute__((address_space(1))) void*)(void*)g,
      (__attribute__((address_space(3))) void*)(void*)l, 16, 0, 0);
}

// ---------------- positional encoding table (L x D, f32) ----------------
__global__ void pe_kernel(float* __restrict__ pe){
  int idx = blockIdx.x*256 + threadIdx.x;
  if (idx >= Ln*Dn) return;
  int l = idx / Dn, d = idx - l*Dn;
  int i = d >> 1;
  float dv = expf((float)(2*i) * (-logf(10000.0f)/(float)Dn));
  float ang = (float)l * dv;
  pe[idx] = (d & 1) ? cosf(ang) : sinf(ang);
}

// ---------------- f32 -> bf16 convert ----------------
__global__ void cvt_kernel(const float* __restrict__ in, ushort* __restrict__ out, int n){
  int i = (blockIdx.x*256 + threadIdx.x)*4;
  if (i >= n) return;
  float4 v = *(const float4*)(in + i);
  ushort4 o;
  o.x = f2bf(v.x); o.y = f2bf(v.y); o.z = f2bf(v.z); o.w = f2bf(v.w);
  *(ushort4*)(out + i) = o;
}

// ---------------- GEMM (m97 structure): C[M x N] = A[M x K](bf16) @ W[N x K]^T ----------------
// BM=BN=128, BK=32, 4 waves (2x2), wave tile 64x64, acc[4][4].
// Staging: global_load_lds width=16, linear LDS [128][32] (64B rows).
// MFMA 16x16x32 bf16; A/B frags share the (g,j)->k bijection k=g*8+j.
// C/D layout: row = (lane>>4)*4 + reg, col = lane&15.
template<int MODE>
__global__ __launch_bounds__(256) void gemm_kernel(
    const ushort* __restrict__ A, const ushort* __restrict__ W,
    const float* __restrict__ bias,
    const float* __restrict__ res,
    const float* __restrict__ spk, const float* __restrict__ pe,
    float* __restrict__ outf, ushort* __restrict__ outb,
    int K, int N, float scale)
{
  __shared__ ushort lA[128][32];
  __shared__ ushort lW[128][32];
  int t = threadIdx.x;
  int wave = t >> 6, lane = t & 63;
  int wr = wave >> 1, wc = wave & 1;
  int g = lane >> 4, r16 = lane & 15;
  int rowBase = blockIdx.y * 128;
  int colBase = blockIdx.x * 128;

  // staging map: chunk c, wave w, lane l -> LDS byte (c*256 + w*64 + l)*16
  //   row = c*64 + w*16 + (l>>2), col = (l&3)*8
  int srow = lane >> 2;
  int scol = (lane & 3) * 8;
  const ushort* gA0 = A + (size_t)(rowBase +      wave*16 + srow)*K + scol;
  const ushort* gA1 = A + (size_t)(rowBase + 64 + wave*16 + srow)*K + scol;
  const ushort* gW0 = W + (size_t)(colBase +      wave*16 + srow)*K + scol;
  const ushort* gW1 = W + (size_t)(colBase + 64 + wave*16 + srow)*K + scol;
  ushort* lA0 = &lA[0][0] + wave*512;
  ushort* lA1 = &lA[0][0] + 2048 + wave*512;
  ushort* lW0 = &lW[0][0] + wave*512;
  ushort* lW1 = &lW[0][0] + 2048 + wave*512;

  f32x4 acc[4][4];
  #pragma unroll
  for (int m=0;m<4;m++)
    #pragma unroll
    for (int n=0;n<4;n++) acc[m][n] = (f32x4)0.0f;

  for (int k0 = 0; k0 < K; k0 += 32){
    gload_lds16(gA0 + k0, lA0);
    gload_lds16(gA1 + k0, lA1);
    gload_lds16(gW0 + k0, lW0);
    gload_lds16(gW1 + k0, lW1);
    __syncthreads();           // drains vmcnt -> tile visible
    short8 af[4], bfr[4];
    #pragma unroll
    for (int m=0;m<4;m++)
      af[m] = *(const short8*)&lA[wr*64 + m*16 + r16][g*8];
    #pragma unroll
    for (int n=0;n<4;n++)
      bfr[n] = *(const short8*)&lW[wc*64 + n*16 + r16][g*8];
    #pragma unroll
    for (int m=0;m<4;m++)
      #pragma unroll
      for (int n=0;n<4;n++)
        acc[m][n] = __builtin_amdgcn_mfma_f32_16x16x32_bf16(af[m], bfr[n], acc[m][n], 0, 0, 0);
    __syncthreads();           // reads done before next-tile overwrite
  }

  #pragma unroll
  for (int m=0;m<4;m++){
    #pragma unroll
    for (int n=0;n<4;n++){
      #pragma unroll
      for (int j=0;j<4;j++){
        int gr = rowBase + wr*64 + m*16 + g*4 + j;
        int gc = colBase + wc*64 + n*16 + r16;
        size_t o = (size_t)gr * N + gc;
        float c = acc[m][n][j];
        if constexpr (MODE == 0){
          float s = 1.0f/(1.0f + expf(-c));
          float rv = s * res[o] + spk[o] + pe[(gr & (Ln-1))*Dn + gc];
          outf[o] = rv; outb[o] = f2bf(rv);
        } else if constexpr (MODE == 1){
          outb[o] = f2bf((c + bias[gc]) * scale);
        } else if constexpr (MODE == 2){
          outf[o] = c + bias[gc] + res[o];
        } else if constexpr (MODE == 3){
          outb[o] = f2bf(gelu_tanh(c + bias[gc]));
        } else {
          outf[o] = gelu_tanh(c + bias[gc]) + res[o];
        }
      }
    }
  }
}

// ---------------- MFMA flash attention ----------------
// grid (L/128, H, B), 256 thr = 4 waves; wave w owns 32 q-rows.
// V^T tile block-XOR swizzled: element (dh,key) stored at
//   lVt[dh][ (key&7) + 8*((key>>3) ^ ((dh>>3)&7)) ]
// -> transposed scalar writes spread across all 32 banks; reads stay 16B b128.
__global__ __launch_bounds__(256) void attn_mfma_kernel(
    const ushort* __restrict__ qb, const ushort* __restrict__ kb, const ushort* __restrict__ vb,
    const int* __restrict__ mask, ushort* __restrict__ ctxb)
{
  __shared__ ushort lK[64][72];
  __shared__ ushort lVt[64][72];   // swizzled [dh][key']
  __shared__ ushort lP[4][32][72]; // wave-private P staging

  int t = threadIdx.x;
  int w = t >> 6, lane = t & 63;
  int g = lane >> 4, r16 = lane & 15;
  int b = blockIdx.z, h = blockIdx.y;
  int qbase = blockIdx.x*128 + w*32;

  short8 af_q[2][2];
  #pragma unroll
  for (int m=0;m<2;m++)
    #pragma unroll
    for (int ks=0;ks<2;ks++)
      af_q[m][ks] = *(const short8*)(qb + (size_t)(b*Ln + qbase + m*16 + r16)*Dn + h*DHn + ks*32 + g*8);

  f32x4 acc_ctx[2][4];
  #pragma unroll
  for (int m=0;m<2;m++)
    #pragma unroll
    for (int n=0;n<4;n++) acc_ctx[m][n] = (f32x4)0.0f;
  float mrun[2][4], lrun[2][4];
  #pragma unroll
  for (int m=0;m<2;m++)
    #pragma unroll
    for (int j=0;j<4;j++){ mrun[m][j] = -INFINITY; lrun[m][j] = 0.0f; }

  for (int kb0 = 0; kb0 < Ln; kb0 += 64){
    __syncthreads();
    #pragma unroll
    for (int i=0;i<2;i++){
      int cid = t + i*256;
      int key = cid >> 3, c8 = (cid & 7)*8;
      short8 kv = *(const short8*)(kb + (size_t)(b*Ln + kb0 + key)*Dn + h*DHn + c8);
      short8 vv = *(const short8*)(vb + (size_t)(b*Ln + kb0 + key)*Dn + h*DHn + c8);
      *(short8*)&lK[key][c8] = kv;
      #pragma unroll
      for (int j=0;j<8;j++){
        int row = c8 + j;                                   // dh
        int colp = (key & 7) + 8*((key >> 3) ^ ((row >> 3) & 7));
        lVt[row][colp] = (ushort)vv[j];
      }
    }
    __syncthreads();

    // S = Q @ K^T
    f32x4 acc_s[2][4];
    #pragma unroll
    for (int m=0;m<2;m++)
      #pragma unroll
      for (int n=0;n<4;n++) acc_s[m][n] = (f32x4)0.0f;
    __builtin_amdgcn_s_setprio(1);
    #pragma unroll
    for (int ks=0;ks<2;ks++){
      short8 bf_k[4];
      #pragma unroll
      for (int n=0;n<4;n++)
        bf_k[n] = *(const short8*)&lK[n*16 + r16][ks*32 + g*8];
      #pragma unroll
      for (int m=0;m<2;m++)
        #pragma unroll
        for (int n=0;n<4;n++)
          acc_s[m][n] = __builtin_amdgcn_mfma_f32_16x16x32_bf16(af_q[m][ks], bf_k[n], acc_s[m][n], 0, 0, 0);
    }
    __builtin_amdgcn_s_setprio(0);

    // mask keys
    #pragma unroll
    for (int n=0;n<4;n++){
      if (mask[b*Ln + kb0 + n*16 + r16] == 0){
        #pragma unroll
        for (int m=0;m<2;m++)
          #pragma unroll
          for (int j=0;j<4;j++) acc_s[m][n][j] = -1e10f;
      }
    }

    // online softmax; P -> bf16 in wave-private LDS
    #pragma unroll
    for (int m=0;m<2;m++){
      #pragma unroll
      for (int j=0;j<4;j++){
        float tmax = fmaxf(fmaxf(acc_s[m][0][j], acc_s[m][1][j]),
                           fmaxf(acc_s[m][2][j], acc_s[m][3][j]));
        #pragma unroll
        for (int off=1; off<16; off<<=1) tmax = fmaxf(tmax, __shfl_xor(tmax, off));
        float newm = fmaxf(mrun[m][j], tmax);
        float alpha = __expf(mrun[m][j] - newm);
        float p0 = __expf(acc_s[m][0][j] - newm);
        float p1 = __expf(acc_s[m][1][j] - newm);
        float p2 = __expf(acc_s[m][2][j] - newm);
        float p3 = __expf(acc_s[m][3][j] - newm);
        float tsum = (p0+p1)+(p2+p3);
        #pragma unroll
        for (int off=1; off<16; off<<=1) tsum += __shfl_xor(tsum, off);
        lrun[m][j] = lrun[m][j]*alpha + tsum;
        mrun[m][j] = newm;
        #pragma unroll
        for (int n2=0;n2<4;n2++) acc_ctx[m][n2][j] *= alpha;
        int prow = m*16 + g*4 + j;
        lP[w][prow][0*16 + r16] = f2bf(p0);
        lP[w][prow][1*16 + r16] = f2bf(p1);
        lP[w][prow][2*16 + r16] = f2bf(p2);
        lP[w][prow][3*16 + r16] = f2bf(p3);
      }
    }

    // ctx += P @ V
    __builtin_amdgcn_s_setprio(1);
    #pragma unroll
    for (int ks2=0;ks2<2;ks2++){
      short8 af_p[2], bf_v[4];
      #pragma unroll
      for (int m=0;m<2;m++)
        af_p[m] = *(const short8*)&lP[w][m*16 + r16][ks2*32 + g*8];
      #pragma unroll
      for (int n=0;n<4;n++){
        int vrow = n*16 + r16;
        int blk = ((ks2*32 + g*8) >> 3) ^ ((vrow >> 3) & 7);
        bf_v[n] = *(const short8*)&lVt[vrow][blk*8];
      }
      #pragma unroll
      for (int m=0;m<2;m++)
        #pragma unroll
        for (int n=0;n<4;n++)
          acc_ctx[m][n] = __builtin_amdgcn_mfma_f32_16x16x32_bf16(af_p[m], bf_v[n], acc_ctx[m][n], 0, 0, 0);
    }
    __builtin_amdgcn_s_setprio(0);
  }

  #pragma unroll
  for (int m=0;m<2;m++){
    #pragma unroll
    for (int j=0;j<4;j++){
      float inv = 1.0f / lrun[m][j];
      int gr = qbase + m*16 + g*4 + j;
      #pragma unroll
      for (int n=0;n<4;n++){
        ctxb[(size_t)(b*Ln + gr)*Dn + h*DHn + n*16 + r16] = f2bf(acc_ctx[m][n][j] * inv);
      }
    }
  }
}

// ---------------- layernorm: one wave per row (D=512), out bf16 ----------------
__global__ __launch_bounds__(256) void ln_kernel(
    const float* __restrict__ hbuf, const float* __restrict__ gamma, const float* __restrict__ beta,
    ushort* __restrict__ out)
{
  int row = blockIdx.x*4 + (threadIdx.x >> 6);
  int lane = threadIdx.x & 63;
  const float* p = hbuf + (size_t)row*Dn + lane*8;
  float4 a = *(const float4*)p;
  float4 c = *(const float4*)(p + 4);
  float v[8] = {a.x,a.y,a.z,a.w,c.x,c.y,c.z,c.w};
  float s = 0.f, ss = 0.f;
  #pragma unroll
  for (int j=0;j<8;j++){ s += v[j]; ss += v[j]*v[j]; }
  #pragma unroll
  for (int off=32; off>0; off>>=1){ s += __shfl_xor(s, off); ss += __shfl_xor(ss, off); }
  float mu = s * (1.0f/Dn);
  float var = ss * (1.0f/Dn) - mu*mu;
  float rstd = rsqrtf(var + 1e-5f);
  ushort o8[8];
  #pragma unroll
  for (int j=0;j<8;j++) o8[j] = f2bf((v[j]-mu)*rstd*gamma[lane*8+j] + beta[lane*8+j]);
  ushort* op = out + (size_t)row*Dn + lane*8;
  *(ushort4*)op       = make_ushort4(o8[0],o8[1],o8[2],o8[3]);
  *(ushort4*)(op + 4) = make_ushort4(o8[4],o8[5],o8[6],o8[7]);
}

extern "C" void kernel_launch(void* const* d_in, const int* in_sizes, int n_in,
                              void* d_out, int out_size, void* d_ws, size_t ws_size,
                              hipStream_t stream) {
  (void)in_sizes; (void)n_in; (void)out_size; (void)ws_size;
  const float* x    = (const float*)d_in[0];
  const int*   mask = (const int*)d_in[1];
  const float* spk  = (const float*)d_in[2];
  const float* Wg   = (const float*)d_in[3];
  const float* Wq   = (const float*)d_in[4];  const float* bq = (const float*)d_in[5];
  const float* Wk   = (const float*)d_in[6];  const float* bk = (const float*)d_in[7];
  const float* Wv   = (const float*)d_in[8];  const float* bv = (const float*)d_in[9];
  const float* Wo   = (const float*)d_in[10]; const float* bo = (const float*)d_in[11];
  const float* lng  = (const float*)d_in[12]; const float* lnbeta = (const float*)d_in[13];
  const float* W1   = (const float*)d_in[14]; const float* b1 = (const float*)d_in[15];
  const float* W2   = (const float*)d_in[16]; const float* b2 = (const float*)d_in[17];
  float* out = (float*)d_out;

  char* w = (char*)d_ws;
  size_t o = 0;
  ushort* xbf   = (ushort*)(w + o); o += (size_t)Mn*Dn*2;   // dead after gate  } overlapped
  ushort* xinb  = (ushort*)(w + o); o += (size_t)Mn*Dn*2;   // dead after v     } by midb
  ushort* qbuf  = (ushort*)(w + o); o += (size_t)Mn*Dn*2;   // dead after attn  } (67.1MB)
  ushort* kbuf  = (ushort*)(w + o); o += (size_t)Mn*Dn*2;   // dead after attn  }
  ushort* vbuf  = (ushort*)(w + o); o += (size_t)Mn*Dn*2;
  ushort* ctxb  = (ushort*)(w + o); o += (size_t)Mn*Dn*2;
  float*  xinf  = (float*)(w + o);  o += (size_t)Mn*Dn*4;
  float*  hbuf  = (float*)(w + o);  o += (size_t)Mn*Dn*4;
  ushort* lnbuf = (ushort*)(w + o); o += (size_t)Mn*Dn*2;
  ushort* wgb   = (ushort*)(w + o); o += (size_t)Dn*Dn*2;
  ushort* wqb   = (ushort*)(w + o); o += (size_t)Dn*Dn*2;
  ushort* wkb   = (ushort*)(w + o); o += (size_t)Dn*Dn*2;
  ushort* wvb   = (ushort*)(w + o); o += (size_t)Dn*Dn*2;
  ushort* wob   = (ushort*)(w + o); o += (size_t)Dn*Dn*2;
  ushort* w1b   = (ushort*)(w + o); o += (size_t)FFn*Dn*2;
  ushort* w2b   = (ushort*)(w + o); o += (size_t)Dn*FFn*2;
  float*  pebuf = (float*)(w + o);  o += (size_t)Ln*Dn*4;
  ushort* midb  = xbf;  // M x FF bf16, overlaps xbf..kbuf (all dead by then)

  hipLaunchKernelGGL(pe_kernel, dim3((Ln*Dn)/256), dim3(256), 0, stream, pebuf);
  hipLaunchKernelGGL(cvt_kernel, dim3((Mn*Dn/4)/256), dim3(256), 0, stream, x, xbf, Mn*Dn);
  hipLaunchKernelGGL(cvt_kernel, dim3((Dn*Dn/4)/256), dim3(256), 0, stream, Wg, wgb, Dn*Dn);
  hipLaunchKernelGGL(cvt_kernel, dim3((Dn*Dn/4)/256), dim3(256), 0, stream, Wq, wqb, Dn*Dn);
  hipLaunchKernelGGL(cvt_kernel, dim3((Dn*Dn/4)/256), dim3(256), 0, stream, Wk, wkb, Dn*Dn);
  hipLaunchKernelGGL(cvt_kernel, dim3((Dn*Dn/4)/256), dim3(256), 0, stream, Wv, wvb, Dn*Dn);
  hipLaunchKernelGGL(cvt_kernel, dim3((Dn*Dn/4)/256), dim3(256), 0, stream, Wo, wob, Dn*Dn);
  hipLaunchKernelGGL(cvt_kernel, dim3((FFn*Dn/4)/256), dim3(256), 0, stream, W1, w1b, FFn*Dn);
  hipLaunchKernelGGL(cvt_kernel, dim3((FFn*Dn/4)/256), dim3(256), 0, stream, W2, w2b, FFn*Dn);

  // gate: xin = sigmoid(x@Wg^T)*x + spk + pe  -> xinf (f32) + xinb (bf16)
  hipLaunchKernelGGL((gemm_kernel<0>), dim3(Dn/128, Mn/128), dim3(256), 0, stream,
                     xbf, wgb, (const float*)nullptr, x, spk, pebuf, xinf, xinb, Dn, Dn, 1.0f);
  // q/k/v
  hipLaunchKernelGGL((gemm_kernel<1>), dim3(Dn/128, Mn/128), dim3(256), 0, stream,
                     xinb, wqb, bq, (const float*)nullptr, (const float*)nullptr, (const float*)nullptr,
                     (float*)nullptr, qbuf, Dn, Dn, 0.125f);
  hipLaunchKernelGGL((gemm_kernel<1>), dim3(Dn/128, Mn/128), dim3(256), 0, stream,
                     xinb, wkb, bk, (const float*)nullptr, (const float*)nullptr, (const float*)nullptr,
                     (float*)nullptr, kbuf, Dn, Dn, 1.0f);
  hipLaunchKernelGGL((gemm_kernel<1>), dim3(Dn/128, Mn/128), dim3(256), 0, stream,
                     xinb, wvb, bv, (const float*)nullptr, (const float*)nullptr, (const float*)nullptr,
                     (float*)nullptr, vbuf, Dn, Dn, 1.0f);
  // attention (MFMA flash)
  hipLaunchKernelGGL(attn_mfma_kernel, dim3(Ln/128, Hn, Bn), dim3(256), 0, stream,
                     qbuf, kbuf, vbuf, mask, ctxb);
  // h = ctx@Wo^T + bo + xin
  hipLaunchKernelGGL((gemm_kernel<2>), dim3(Dn/128, Mn/128), dim3(256), 0, stream,
                     ctxb, wob, bo, xinf, (const float*)nullptr, (const float*)nullptr,
                     hbuf, (ushort*)nullptr, Dn, Dn, 1.0f);
  // layernorm
  hipLaunchKernelGGL(ln_kernel, dim3(Mn/4), dim3(256), 0, stream, hbuf, lng, lnbeta, lnbuf);
  // mid = gelu(ln@W1^T + b1)
  hipLaunchKernelGGL((gemm_kernel<3>), dim3(FFn/128, Mn/128), dim3(256), 0, stream,
                     lnbuf, w1b, b1, (const float*)nullptr, (const float*)nullptr, (const float*)nullptr,
                     (float*)nullptr, midb, Dn, FFn, 1.0f);
  // out = gelu(mid@W2^T + b2) + h
  hipLaunchKernelGGL((gemm_kernel<4>), dim3(Dn/128, Mn/128), dim3(256), 0, stream,
                     midb, w2b, b2, hbuf, (const float*)nullptr, (const float*)nullptr,
                     out, (ushort*)nullptr, FFn, Dn, 1.0f);
}

// Round 4
// 318.809 us; speedup vs baseline: 2.2423x; 1.2020x over previous
//
#include <hip/hip_runtime.h>
#include <math.h>

#define Bn 32
#define Ln 512
#define Dn 512
#define Hn 8
#define DHn 64
#define FFn 2048
#define Mn (Bn*Ln)   // 16384
#define QKVS 1536

typedef __attribute__((ext_vector_type(4))) float f32x4;
typedef __attribute__((ext_vector_type(8))) short short8;

__device__ __forceinline__ float bf2f(ushort u){ return __uint_as_float(((unsigned)u) << 16); }
__device__ __forceinline__ ushort f2bf(float f){
  unsigned u = __float_as_uint(f);
  u += 0x7FFFu + ((u >> 16) & 1u);
  return (ushort)(u >> 16);
}
// exact sigmoid-form of tanh-gelu: 0.5x(1+tanh(y)) == x*sigmoid(2y)
__device__ __forceinline__ float gelu_fast(float x){
  float y2 = 1.5957691216057308f * (x + 0.044715f*x*x*x);
  return x / (1.0f + __expf(-y2));
}

// async global->LDS, 16B per lane; LDS dest is wave-uniform base + lane*16
__device__ __forceinline__ void gload_lds16(const ushort* g, ushort* l){
  __builtin_amdgcn_global_load_lds(
      (__attribute__((address_space(1))) void*)(void*)g,
      (__attribute__((address_space(3))) void*)(void*)l, 16, 0, 0);
}

// ---------------- positional encoding table (L x D, f32) ----------------
__global__ void pe_kernel(float* __restrict__ pe){
  int idx = blockIdx.x*256 + threadIdx.x;
  if (idx >= Ln*Dn) return;
  int l = idx / Dn, d = idx - l*Dn;
  int i = d >> 1;
  float dv = expf((float)(2*i) * (-logf(10000.0f)/(float)Dn));
  float ang = (float)l * dv;
  pe[idx] = (d & 1) ? cosf(ang) : sinf(ang);
}

// ---------------- f32 -> bf16 convert ----------------
__global__ void cvt_kernel(const float* __restrict__ in, ushort* __restrict__ out, int n){
  int i = (blockIdx.x*256 + threadIdx.x)*4;
  if (i >= n) return;
  float4 v = *(const float4*)(in + i);
  ushort4 o;
  o.x = f2bf(v.x); o.y = f2bf(v.y); o.z = f2bf(v.z); o.w = f2bf(v.w);
  *(ushort4*)(out + i) = o;
}

__global__ void pack_bias_kernel(const float* __restrict__ bq, const float* __restrict__ bk,
                                 const float* __restrict__ bv, float* __restrict__ out){
  int i = blockIdx.x*256 + threadIdx.x;
  if (i >= QKVS) return;
  out[i] = (i < 512) ? bq[i] : (i < 1024) ? bk[i-512] : bv[i-1024];
}

// ---------------- GEMM: C[M x N] = A[M x K](bf16) @ W[N x K]^T, f32 acc ----------------
// BM=BN=128, BK=64, 4 waves (2x2), wave tile 64x64, acc[4][4], 32 MFMA / K-step.
// Staging: global_load_lds w=16, LINEAR dest; source column pre-swizzled so that
// logical (row,u) lives at u_phys = u ^ (row&7)  (G4 XOR swizzle, both-sides).
// Reads apply the same XOR -> 2 lanes/bank (free).
// Grid: 1D nwg = (N/128)*(M/128), XCD-bijective remap (m157), col-fastest decode.
// MODE: 0 gate  1 qkv(bias pack + q-scale)  2 bias+res->f32  3 gelu->bf16  4 gelu+res->f32
template<int MODE>
__global__ __launch_bounds__(256) void gemm_kernel(
    const ushort* __restrict__ A, const ushort* __restrict__ W,
    const float* __restrict__ bias,
    const float* __restrict__ res,
    const float* __restrict__ spk, const float* __restrict__ pe,
    float* __restrict__ outf, ushort* __restrict__ outb,
    int K, int N, int gx)
{
  __shared__ ushort lA[128][64];
  __shared__ ushort lW[128][64];
  int t = threadIdx.x;
  int wave = t >> 6, lane = t & 63;
  int wr = wave >> 1, wc = wave & 1;
  int g = lane >> 4, r16 = lane & 15;

  // XCD-bijective tile remap: nwg = gx*128 (always %8==0)
  int nwg = gx << 7;
  int wg = blockIdx.x;
  int tile = (wg & 7)*(nwg >> 3) + (wg >> 3);
  int trow = tile / gx;
  int tcol = tile - trow*gx;
  int rowBase = trow * 128;
  int colBase = tcol * 128;

  // staging: lane l writes 16B unit (wave*64 + c*256 + l) -> row = c*32+wave*8+(l>>3), u_phys = l&7
  // source must hold u_log = u_phys ^ (row&7) = (l&7) ^ (l>>3)
  int srow8 = lane >> 3;
  int sucol = ((lane & 7) ^ srow8) * 8;
  const ushort* gA = A + (size_t)(rowBase + wave*8 + srow8)*K + sucol;
  const ushort* gW = W + (size_t)(colBase + wave*8 + srow8)*K + sucol;
  ushort* lAbase = &lA[0][0] + wave*512;
  ushort* lWbase = &lW[0][0] + wave*512;

  f32x4 acc[4][4];
  #pragma unroll
  for (int m=0;m<4;m++)
    #pragma unroll
    for (int n=0;n<4;n++) acc[m][n] = (f32x4)0.0f;

  for (int k0 = 0; k0 < K; k0 += 64){
    #pragma unroll
    for (int c=0;c<4;c++){
      gload_lds16(gA + (size_t)c*32*K + k0, lAbase + c*2048);
      gload_lds16(gW + (size_t)c*32*K + k0, lWbase + c*2048);
    }
    __syncthreads();           // drains vmcnt -> tile visible
    #pragma unroll
    for (int ks=0; ks<2; ks++){
      short8 af[4], bfr[4];
      #pragma unroll
      for (int m=0;m<4;m++){
        int row = wr*64 + m*16 + r16;
        af[m] = *(const short8*)&lA[row][(((ks<<2)+g) ^ (r16 & 7))*8];
      }
      #pragma unroll
      for (int n=0;n<4;n++){
        int row = wc*64 + n*16 + r16;
        bfr[n] = *(const short8*)&lW[row][(((ks<<2)+g) ^ (r16 & 7))*8];
      }
      #pragma unroll
      for (int m=0;m<4;m++)
        #pragma unroll
        for (int n=0;n<4;n++)
          acc[m][n] = __builtin_amdgcn_mfma_f32_16x16x32_bf16(af[m], bfr[n], acc[m][n], 0, 0, 0);
    }
    __syncthreads();           // reads done before next-tile overwrite
  }

  #pragma unroll
  for (int m=0;m<4;m++){
    #pragma unroll
    for (int n=0;n<4;n++){
      #pragma unroll
      for (int j=0;j<4;j++){
        int gr = rowBase + wr*64 + m*16 + g*4 + j;
        int gc = colBase + wc*64 + n*16 + r16;
        size_t o = (size_t)gr * N + gc;
        float c = acc[m][n][j];
        if constexpr (MODE == 0){
          float s = 1.0f/(1.0f + __expf(-c));
          float rv = s * res[o] + spk[o] + pe[(gr & (Ln-1))*Dn + gc];
          outf[o] = rv; outb[o] = f2bf(rv);
        } else if constexpr (MODE == 1){
          float sc = (gc < 512) ? 0.125f : 1.0f;
          outb[o] = f2bf((c + bias[gc]) * sc);
        } else if constexpr (MODE == 2){
          outf[o] = c + bias[gc] + res[o];
        } else if constexpr (MODE == 3){
          outb[o] = f2bf(gelu_fast(c + bias[gc]));
        } else {
          outf[o] = gelu_fast(c + bias[gc]) + res[o];
        }
      }
    }
  }
}

// ---------------- MFMA flash attention ----------------
// grid (L/128, H, B), 256 thr = 4 waves; wave w owns 32 q-rows.
// q/k/v read from fused [M][1536] buffer (stride QKVS).
// V^T tile block-XOR swizzled; K tile row-padded [64][72].
__global__ __launch_bounds__(256) void attn_mfma_kernel(
    const ushort* __restrict__ qb, const ushort* __restrict__ kb, const ushort* __restrict__ vb,
    const int* __restrict__ mask, ushort* __restrict__ ctxb)
{
  __shared__ ushort lK[64][72];
  __shared__ ushort lVt[64][72];   // swizzled [dh][key']
  __shared__ ushort lP[4][32][72]; // wave-private P staging

  int t = threadIdx.x;
  int w = t >> 6, lane = t & 63;
  int g = lane >> 4, r16 = lane & 15;
  int b = blockIdx.z, h = blockIdx.y;
  int qbase = blockIdx.x*128 + w*32;

  short8 af_q[2][2];
  #pragma unroll
  for (int m=0;m<2;m++)
    #pragma unroll
    for (int ks=0;ks<2;ks++)
      af_q[m][ks] = *(const short8*)(qb + (size_t)(b*Ln + qbase + m*16 + r16)*QKVS + h*DHn + ks*32 + g*8);

  f32x4 acc_ctx[2][4];
  #pragma unroll
  for (int m=0;m<2;m++)
    #pragma unroll
    for (int n=0;n<4;n++) acc_ctx[m][n] = (f32x4)0.0f;
  float mrun[2][4], lrun[2][4];
  #pragma unroll
  for (int m=0;m<2;m++)
    #pragma unroll
    for (int j=0;j<4;j++){ mrun[m][j] = -INFINITY; lrun[m][j] = 0.0f; }

  for (int kb0 = 0; kb0 < Ln; kb0 += 64){
    __syncthreads();
    #pragma unroll
    for (int i=0;i<2;i++){
      int cid = t + i*256;
      int key = cid >> 3, c8 = (cid & 7)*8;
      short8 kv = *(const short8*)(kb + (size_t)(b*Ln + kb0 + key)*QKVS + h*DHn + c8);
      short8 vv = *(const short8*)(vb + (size_t)(b*Ln + kb0 + key)*QKVS + h*DHn + c8);
      *(short8*)&lK[key][c8] = kv;
      #pragma unroll
      for (int j=0;j<8;j++){
        int row = c8 + j;                                   // dh
        int colp = (key & 7) + 8*((key >> 3) ^ ((row >> 3) & 7));
        lVt[row][colp] = (ushort)vv[j];
      }
    }
    __syncthreads();

    // S = Q @ K^T
    f32x4 acc_s[2][4];
    #pragma unroll
    for (int m=0;m<2;m++)
      #pragma unroll
      for (int n=0;n<4;n++) acc_s[m][n] = (f32x4)0.0f;
    __builtin_amdgcn_s_setprio(1);
    #pragma unroll
    for (int ks=0;ks<2;ks++){
      short8 bf_k[4];
      #pragma unroll
      for (int n=0;n<4;n++)
        bf_k[n] = *(const short8*)&lK[n*16 + r16][ks*32 + g*8];
      #pragma unroll
      for (int m=0;m<2;m++)
        #pragma unroll
        for (int n=0;n<4;n++)
          acc_s[m][n] = __builtin_amdgcn_mfma_f32_16x16x32_bf16(af_q[m][ks], bf_k[n], acc_s[m][n], 0, 0, 0);
    }
    __builtin_amdgcn_s_setprio(0);

    // mask keys
    #pragma unroll
    for (int n=0;n<4;n++){
      if (mask[b*Ln + kb0 + n*16 + r16] == 0){
        #pragma unroll
        for (int m=0;m<2;m++)
          #pragma unroll
          for (int j=0;j<4;j++) acc_s[m][n][j] = -1e10f;
      }
    }

    // online softmax; P -> bf16 in wave-private LDS
    #pragma unroll
    for (int m=0;m<2;m++){
      #pragma unroll
      for (int j=0;j<4;j++){
        float tmax = fmaxf(fmaxf(acc_s[m][0][j], acc_s[m][1][j]),
                           fmaxf(acc_s[m][2][j], acc_s[m][3][j]));
        #pragma unroll
        for (int off=1; off<16; off<<=1) tmax = fmaxf(tmax, __shfl_xor(tmax, off));
        float newm = fmaxf(mrun[m][j], tmax);
        float alpha = __expf(mrun[m][j] - newm);
        float p0 = __expf(acc_s[m][0][j] - newm);
        float p1 = __expf(acc_s[m][1][j] - newm);
        float p2 = __expf(acc_s[m][2][j] - newm);
        float p3 = __expf(acc_s[m][3][j] - newm);
        float tsum = (p0+p1)+(p2+p3);
        #pragma unroll
        for (int off=1; off<16; off<<=1) tsum += __shfl_xor(tsum, off);
        lrun[m][j] = lrun[m][j]*alpha + tsum;
        mrun[m][j] = newm;
        #pragma unroll
        for (int n2=0;n2<4;n2++) acc_ctx[m][n2][j] *= alpha;
        int prow = m*16 + g*4 + j;
        lP[w][prow][0*16 + r16] = f2bf(p0);
        lP[w][prow][1*16 + r16] = f2bf(p1);
        lP[w][prow][2*16 + r16] = f2bf(p2);
        lP[w][prow][3*16 + r16] = f2bf(p3);
      }
    }

    // ctx += P @ V
    __builtin_amdgcn_s_setprio(1);
    #pragma unroll
    for (int ks2=0;ks2<2;ks2++){
      short8 af_p[2], bf_v[4];
      #pragma unroll
      for (int m=0;m<2;m++)
        af_p[m] = *(const short8*)&lP[w][m*16 + r16][ks2*32 + g*8];
      #pragma unroll
      for (int n=0;n<4;n++){
        int vrow = n*16 + r16;
        int blk = ((ks2*32 + g*8) >> 3) ^ ((vrow >> 3) & 7);
        bf_v[n] = *(const short8*)&lVt[vrow][blk*8];
      }
      #pragma unroll
      for (int m=0;m<2;m++)
        #pragma unroll
        for (int n=0;n<4;n++)
          acc_ctx[m][n] = __builtin_amdgcn_mfma_f32_16x16x32_bf16(af_p[m], bf_v[n], acc_ctx[m][n], 0, 0, 0);
    }
    __builtin_amdgcn_s_setprio(0);
  }

  #pragma unroll
  for (int m=0;m<2;m++){
    #pragma unroll
    for (int j=0;j<4;j++){
      float inv = 1.0f / lrun[m][j];
      int gr = qbase + m*16 + g*4 + j;
      #pragma unroll
      for (int n=0;n<4;n++){
        ctxb[(size_t)(b*Ln + gr)*Dn + h*DHn + n*16 + r16] = f2bf(acc_ctx[m][n][j] * inv);
      }
    }
  }
}

// ---------------- layernorm: one wave per row (D=512), out bf16 ----------------
__global__ __launch_bounds__(256) void ln_kernel(
    const float* __restrict__ hbuf, const float* __restrict__ gamma, const float* __restrict__ beta,
    ushort* __restrict__ out)
{
  int row = blockIdx.x*4 + (threadIdx.x >> 6);
  int lane = threadIdx.x & 63;
  const float* p = hbuf + (size_t)row*Dn + lane*8;
  float4 a = *(const float4*)p;
  float4 c = *(const float4*)(p + 4);
  float v[8] = {a.x,a.y,a.z,a.w,c.x,c.y,c.z,c.w};
  float s = 0.f, ss = 0.f;
  #pragma unroll
  for (int j=0;j<8;j++){ s += v[j]; ss += v[j]*v[j]; }
  #pragma unroll
  for (int off=32; off>0; off>>=1){ s += __shfl_xor(s, off); ss += __shfl_xor(ss, off); }
  float mu = s * (1.0f/Dn);
  float var = ss * (1.0f/Dn) - mu*mu;
  float rstd = rsqrtf(var + 1e-5f);
  ushort o8[8];
  #pragma unroll
  for (int j=0;j<8;j++) o8[j] = f2bf((v[j]-mu)*rstd*gamma[lane*8+j] + beta[lane*8+j]);
  ushort* op = out + (size_t)row*Dn + lane*8;
  *(ushort4*)op       = make_ushort4(o8[0],o8[1],o8[2],o8[3]);
  *(ushort4*)(op + 4) = make_ushort4(o8[4],o8[5],o8[6],o8[7]);
}

extern "C" void kernel_launch(void* const* d_in, const int* in_sizes, int n_in,
                              void* d_out, int out_size, void* d_ws, size_t ws_size,
                              hipStream_t stream) {
  (void)in_sizes; (void)n_in; (void)out_size; (void)ws_size;
  const float* x    = (const float*)d_in[0];
  const int*   mask = (const int*)d_in[1];
  const float* spk  = (const float*)d_in[2];
  const float* Wg   = (const float*)d_in[3];
  const float* Wq   = (const float*)d_in[4];  const float* bq = (const float*)d_in[5];
  const float* Wk   = (const float*)d_in[6];  const float* bk = (const float*)d_in[7];
  const float* Wv   = (const float*)d_in[8];  const float* bv = (const float*)d_in[9];
  const float* Wo   = (const float*)d_in[10]; const float* bo = (const float*)d_in[11];
  const float* lng  = (const float*)d_in[12]; const float* lnbeta = (const float*)d_in[13];
  const float* W1   = (const float*)d_in[14]; const float* b1 = (const float*)d_in[15];
  const float* W2   = (const float*)d_in[16]; const float* b2 = (const float*)d_in[17];
  float* out = (float*)d_out;

  char* w = (char*)d_ws;
  size_t o = 0;
  ushort* xbf   = (ushort*)(w + o); o += (size_t)Mn*Dn*2;    // dead after gate   } overlapped
  ushort* xinb  = (ushort*)(w + o); o += (size_t)Mn*Dn*2;    // dead after qkv    } by midb
  ushort* qkvb  = (ushort*)(w + o); o += (size_t)Mn*QKVS*2;  // dead after attn   } (67.1MB need)
  ushort* ctxb  = (ushort*)(w + o); o += (size_t)Mn*Dn*2;
  float*  xinf  = (float*)(w + o);  o += (size_t)Mn*Dn*4;
  float*  hbuf  = (float*)(w + o);  o += (size_t)Mn*Dn*4;
  ushort* lnbuf = (ushort*)(w + o); o += (size_t)Mn*Dn*2;
  ushort* wgb   = (ushort*)(w + o); o += (size_t)Dn*Dn*2;
  ushort* wqkvb = (ushort*)(w + o); o += (size_t)QKVS*Dn*2;
  ushort* wob   = (ushort*)(w + o); o += (size_t)Dn*Dn*2;
  ushort* w1b   = (ushort*)(w + o); o += (size_t)FFn*Dn*2;
  ushort* w2b   = (ushort*)(w + o); o += (size_t)Dn*FFn*2;
  float*  pebuf = (float*)(w + o);  o += (size_t)Ln*Dn*4;
  float*  bqkv  = (float*)(w + o);  o += (size_t)QKVS*4;
  ushort* midb  = xbf;  // M x FF bf16 (67MB), overlaps xbf+xinb+qkvb (84MB, all dead by ff1)

  hipLaunchKernelGGL(pe_kernel, dim3((Ln*Dn)/256), dim3(256), 0, stream, pebuf);
  hipLaunchKernelGGL(cvt_kernel, dim3((Mn*Dn/4)/256), dim3(256), 0, stream, x, xbf, Mn*Dn);
  hipLaunchKernelGGL(cvt_kernel, dim3((Dn*Dn/4)/256), dim3(256), 0, stream, Wg, wgb, Dn*Dn);
  hipLaunchKernelGGL(cvt_kernel, dim3((Dn*Dn/4)/256), dim3(256), 0, stream, Wq, wqkvb,            Dn*Dn);
  hipLaunchKernelGGL(cvt_kernel, dim3((Dn*Dn/4)/256), dim3(256), 0, stream, Wk, wqkvb + Dn*Dn,    Dn*Dn);
  hipLaunchKernelGGL(cvt_kernel, dim3((Dn*Dn/4)/256), dim3(256), 0, stream, Wv, wqkvb + 2*Dn*Dn,  Dn*Dn);
  hipLaunchKernelGGL(cvt_kernel, dim3((Dn*Dn/4)/256), dim3(256), 0, stream, Wo, wob, Dn*Dn);
  hipLaunchKernelGGL(cvt_kernel, dim3((FFn*Dn/4)/256), dim3(256), 0, stream, W1, w1b, FFn*Dn);
  hipLaunchKernelGGL(cvt_kernel, dim3((FFn*Dn/4)/256), dim3(256), 0, stream, W2, w2b, FFn*Dn);
  hipLaunchKernelGGL(pack_bias_kernel, dim3((QKVS+255)/256), dim3(256), 0, stream, bq, bk, bv, bqkv);

  // gate: xin = sigmoid(x@Wg^T)*x + spk + pe  -> xinf (f32) + xinb (bf16)
  hipLaunchKernelGGL((gemm_kernel<0>), dim3((Dn/128)*(Mn/128)), dim3(256), 0, stream,
                     xbf, wgb, (const float*)nullptr, x, spk, pebuf, xinf, xinb, Dn, Dn, Dn/128);
  // fused qkv: [M][1536]
  hipLaunchKernelGGL((gemm_kernel<1>), dim3((QKVS/128)*(Mn/128)), dim3(256), 0, stream,
                     xinb, wqkvb, bqkv, (const float*)nullptr, (const float*)nullptr, (const float*)nullptr,
                     (float*)nullptr, qkvb, Dn, QKVS, QKVS/128);
  // attention (MFMA flash)
  hipLaunchKernelGGL(attn_mfma_kernel, dim3(Ln/128, Hn, Bn), dim3(256), 0, stream,
                     qkvb, qkvb + 512, qkvb + 1024, mask, ctxb);
  // h = ctx@Wo^T + bo + xin
  hipLaunchKernelGGL((gemm_kernel<2>), dim3((Dn/128)*(Mn/128)), dim3(256), 0, stream,
                     ctxb, wob, bo, xinf, (const float*)nullptr, (const float*)nullptr,
                     hbuf, (ushort*)nullptr, Dn, Dn, Dn/128);
  // layernorm
  hipLaunchKernelGGL(ln_kernel, dim3(Mn/4), dim3(256), 0, stream, hbuf, lng, lnbeta, lnbuf);
  // mid = gelu(ln@W1^T + b1)
  hipLaunchKernelGGL((gemm_kernel<3>), dim3((FFn/128)*(Mn/128)), dim3(256), 0, stream,
                     lnbuf, w1b, b1, (const float*)nullptr, (const float*)nullptr, (const float*)nullptr,
                     (float*)nullptr, midb, Dn, FFn, FFn/128);
  // out = gelu(mid@W2^T + b2) + h
  hipLaunchKernelGGL((gemm_kernel<4>), dim3((Dn/128)*(Mn/128)), dim3(256), 0, stream,
                     midb, w2b, b2, hbuf, (const float*)nullptr, (const float*)nullptr,
                     out, (ushort*)nullptr, FFn, Dn, Dn/128);
}